// Round 6
// baseline (186.600 us; speedup 1.0000x reference)
//
#include <hip/hip_runtime.h>

typedef unsigned short u16;
typedef __bf16 bf16x8 __attribute__((ext_vector_type(8)));
typedef float f32x4 __attribute__((ext_vector_type(4)));

__device__ __forceinline__ u16 f2bf(float f) {
  unsigned int u = __float_as_uint(f);
  u += 0x7fffu + ((u >> 16) & 1u);
  return (u16)(u >> 16);
}
__device__ __forceinline__ float bf2f(u16 v) {
  return __uint_as_float(((unsigned)v) << 16);
}

#define GLDS16(gp, lp)                                                   \
  __builtin_amdgcn_global_load_lds(                                      \
      (const __attribute__((address_space(1))) unsigned int*)(gp),       \
      (__attribute__((address_space(3))) unsigned int*)(lp), 16, 0, 0)

// B=8, C=256, L=4096, M=32768, NHEAD=8, dim=32
// ws layout (bytes)
#define OFF_WQ     0u
#define OFF_WK     131072u     /* wkvt rows 0:256 */
#define OFF_WV     262144u
#define OFF_WM     393216u
#define OFF_W1     524288u
#define OFF_W2     1048576u
#define OFF_CAT    1310720u    /* u16 [M][512]: 0:256 xs, 256:512 ln1 */
#define OFF_SSB    34865152u   /* u16 [M][256] ss_bf16 */
#define OFF_KVPROJ 68419584u   /* u16 [M][512] K|vals bf16 */
#define OFF_KV     152305664u  /* f32 [64][32][32] */
#define OFF_KS     152567808u  /* f32 [64][32] */
#define OFF_KVP    152576000u  /* f32 [8][64][32][32] partials ; later wcomb */
#define OFF_KSP    154673152u  /* f32 [8][64][32] partials */

// ---- transposes fp32 [C,L] -> bf16 [L,C] ------------------------------------
__global__ __launch_bounds__(256) void transpose_in_kernel(
    const float* __restrict__ x, const float* __restrict__ srcp,
    u16* __restrict__ cat, u16* __restrict__ ssb) {
  __shared__ float s[32][33];
  int z = blockIdx.z;
  const float* src = z < 8 ? x : srcp;
  u16* dst = z < 8 ? cat : ssb;
  int dstride = z < 8 ? 512 : 256;
  int b = z & 7;
  int lt = blockIdx.x * 32, ct = blockIdx.y * 32;
  int tx = threadIdx.x & 31, ty = threadIdx.x >> 5;
#pragma unroll
  for (int i = 0; i < 4; ++i)
    s[ty + i * 8][tx] = src[((size_t)b * 256 + ct + ty + i * 8) * 4096 + lt + tx];
  __syncthreads();
#pragma unroll
  for (int i = 0; i < 4; ++i)
    dst[((size_t)b * 4096 + lt + ty + i * 8) * dstride + ct + tx] = f2bf(s[tx][ty + i * 8]);
}

// ---- weight prep: fp32 [K,N] -> bf16 [N,K], all weights one dispatch --------
__global__ __launch_bounds__(256) void wprep_all_kernel(
    const float* __restrict__ Wq, const float* __restrict__ Wk,
    const float* __restrict__ Wv, const float* __restrict__ Wm,
    const float* __restrict__ W1, const float* __restrict__ W2,
    u16* __restrict__ dq, u16* __restrict__ dk, u16* __restrict__ dv,
    u16* __restrict__ dm, u16* __restrict__ d1, u16* __restrict__ d2) {
  __shared__ float s[32][33];
  int bid = blockIdx.x;
  const float* src; u16* dst; int Kd, Nd, t;
  if (bid < 64)       { src = Wq; dst = dq; Kd = 256; Nd = 256; t = bid; }
  else if (bid < 128) { src = Wk; dst = dk; Kd = 256; Nd = 256; t = bid - 64; }
  else if (bid < 192) { src = Wv; dst = dv; Kd = 256; Nd = 256; t = bid - 128; }
  else if (bid < 256) { src = Wm; dst = dm; Kd = 256; Nd = 256; t = bid - 192; }
  else if (bid < 512) { src = W1; dst = d1; Kd = 512; Nd = 512; t = bid - 256; }
  else                { src = W2; dst = d2; Kd = 512; Nd = 256; t = bid - 512; }
  int ntn = Nd >> 5;
  int kt = (t / ntn) * 32, nt = (t % ntn) * 32;
  int tx = threadIdx.x & 31, ty = threadIdx.x >> 5;
#pragma unroll
  for (int i = 0; i < 4; ++i)
    s[ty + i * 8][tx] = src[(size_t)(kt + ty + i * 8) * Nd + nt + tx];
  __syncthreads();
#pragma unroll
  for (int i = 0; i < 4; ++i)
    dst[(size_t)(nt + ty + i * 8) * Kd + kt + tx] = f2bf(s[tx][ty + i * 8]);
}

// ---- bf16 MFMA GEMM, 128x128 tile, 4 waves, gload_lds, XCD-chunked grid -----
// EPI 4: fused kv (col<256 elu+1, else /4096) bf16
template <int EPI>
__global__ __launch_bounds__(256) void gemm_kernel(
    const u16* __restrict__ A, int lda, const u16* __restrict__ Wt, int K,
    u16* __restrict__ outp, int ldo) {
  __shared__ alignas(16) u16 sA[128 * 64];
  __shared__ alignas(16) u16 sB[128 * 64];
  const int tid = threadIdx.x;
  int bid = blockIdx.x;
  int xcd = bid & 7, i0 = bid >> 3;
  const int m0 = (xcd * 32 + (i0 >> 2)) * 128;
  const int n0 = (i0 & 3) * 128;
  const int w = tid >> 6, lane = tid & 63;
  const int wm = (w >> 1) * 64, wn = (w & 1) * 64;
  const int lr = lane & 15, lk = lane >> 4;
  f32x4 acc[4][4] = {};
  const int srow = tid >> 3, sch = (tid & 7) << 3;
  const u16* ga = A + (size_t)(m0 + srow) * lda + sch;
  const u16* gb = Wt + (size_t)(n0 + srow) * K + sch;

  const int nkt = K >> 6;
  for (int kt = 0; kt < nkt; ++kt) {
    __syncthreads();
#pragma unroll
    for (int i = 0; i < 4; ++i) {
      GLDS16(ga + (size_t)i * 32 * lda + kt * 64, sA + (tid + i * 256) * 8);
      GLDS16(gb + (size_t)i * 32 * K + kt * 64, sB + (tid + i * 256) * 8);
    }
    __syncthreads();
    bf16x8 af[4][2], bfr[4][2];
#pragma unroll
    for (int f = 0; f < 4; ++f) {
#pragma unroll
      for (int ks = 0; ks < 2; ++ks) {
        af[f][ks] = *reinterpret_cast<const bf16x8*>(
            &sA[(wm + f * 16 + lr) * 64 + ks * 32 + lk * 8]);
        bfr[f][ks] = *reinterpret_cast<const bf16x8*>(
            &sB[(wn + f * 16 + lr) * 64 + ks * 32 + lk * 8]);
      }
    }
#pragma unroll
    for (int ks = 0; ks < 2; ++ks)
#pragma unroll
      for (int fm = 0; fm < 4; ++fm)
#pragma unroll
        for (int fn = 0; fn < 4; ++fn)
          acc[fm][fn] = __builtin_amdgcn_mfma_f32_16x16x32_bf16(
              af[fm][ks], bfr[fn][ks], acc[fm][fn], 0, 0, 0);
  }

  const int r0 = (lane >> 4) * 4, c0 = lane & 15;
#pragma unroll
  for (int fm = 0; fm < 4; ++fm) {
#pragma unroll
    for (int fn = 0; fn < 4; ++fn) {
      int gr = m0 + wm + fm * 16 + r0;
      int gc = n0 + wn + fn * 16 + c0;
#pragma unroll
      for (int r = 0; r < 4; ++r) {
        float v = acc[fm][fn][r];
        if (EPI == 4) v = (gc < 256) ? (v > 0.f ? v + 1.f : __expf(v)) : v * (1.f / 4096.f);
        outp[(size_t)(gr + r) * ldo + gc] = f2bf(v);
      }
    }
  }
}

// ---- KV partial over L-slices (reads bf16 kvproj [M][512]) ------------------
__global__ __launch_bounds__(256) void kv_partial_kernel(
    const u16* __restrict__ KVproj, float* __restrict__ KVp,
    float* __restrict__ KSp) {
  __shared__ alignas(16) float sK[64][32];
  __shared__ alignas(16) float sV[64][32];
  const int bh = blockIdx.x, sl = blockIdx.y;
  const int b = bh >> 3, h = bh & 7;
  const int t = threadIdx.x;
  const int lrow = t >> 2, lcol = (t & 3) * 8;
  const int d = t >> 3, vg = (t & 7) * 4;
  float a0 = 0, a1 = 0, a2 = 0, a3 = 0, ks = 0;
  for (int lt = 0; lt < 512; lt += 64) {
    __syncthreads();
    size_t roff = ((size_t)b * 4096 + sl * 512 + lt + lrow) * 512 + h * 32 + lcol;
    uint4 kq = *reinterpret_cast<const uint4*>(KVproj + roff);
    uint4 vq = *reinterpret_cast<const uint4*>(KVproj + roff + 256);
    float* dk = &sK[lrow][lcol];
    float* dv = &sV[lrow][lcol];
#pragma unroll
    for (int j = 0; j < 4; ++j) {
      unsigned uk = ((const unsigned*)&kq)[j];
      unsigned uv = ((const unsigned*)&vq)[j];
      dk[2 * j] = __uint_as_float(uk << 16);
      dk[2 * j + 1] = __uint_as_float(uk & 0xffff0000u);
      dv[2 * j] = __uint_as_float(uv << 16);
      dv[2 * j + 1] = __uint_as_float(uv & 0xffff0000u);
    }
    __syncthreads();
#pragma unroll 8
    for (int i = 0; i < 64; ++i) {
      float kd = sK[i][d];
      a0 += kd * sV[i][vg + 0];
      a1 += kd * sV[i][vg + 1];
      a2 += kd * sV[i][vg + 2];
      a3 += kd * sV[i][vg + 3];
      ks += kd;
    }
  }
  float* o = KVp + (size_t)sl * 65536 + bh * 1024 + d * 32 + vg;
  o[0] = a0; o[1] = a1; o[2] = a2; o[3] = a3;
  if ((t & 7) == 0) KSp[(size_t)sl * 2048 + bh * 32 + d] = ks;
}

__global__ __launch_bounds__(256) void kv_reduce_kernel(
    const float* __restrict__ KVp, const float* __restrict__ KSp,
    float* __restrict__ KV, float* __restrict__ Ksum) {
  int gid = blockIdx.x * 256 + threadIdx.x;
  if (gid < 65536) {
    float s = 0;
#pragma unroll
    for (int i = 0; i < 8; ++i) s += KVp[(size_t)i * 65536 + gid];
    KV[gid] = s;
  } else if (gid - 65536 < 2048) {
    int j = gid - 65536;
    float s = 0;
#pragma unroll
    for (int i = 0; i < 8; ++i) s += KSp[(size_t)i * 2048 + j];
    Ksum[j] = s;
  }
}

// ---- W_comb[b][n][k] = sum_v KV[b,h(k),d(k),v] * WmT[n][h*32+v] -> bf16 -----
__global__ __launch_bounds__(256) void wcomb_kernel(
    const float* __restrict__ KVb, const u16* __restrict__ wmt,
    u16* __restrict__ wc) {
  const int bid = blockIdx.x;  // 0..2047
  const int b = bid >> 8, n = bid & 255;
  const int k = threadIdx.x, h = k >> 5, d = k & 31;
  const float* kv = KVb + ((size_t)b * 8 + h) * 1024 + d * 32;
  const u16* wm = wmt + (size_t)n * 256 + h * 32;
  float s = 0.f;
#pragma unroll
  for (int v = 0; v < 32; ++v) s += kv[v] * bf2f(wm[v]);
  wc[((size_t)b * 256 + n) * 256 + k] = f2bf(s);
}

// ---- FUSED: Qproj + elu+1 + z-scale + (Qs @ Wcomb) + LN1 -> cat[:,256:512] --
// BM=64, 256 threads (4 waves, 1m x 4n: wave tile 64x64), grid 512.
// LDS: phase1 sA@0 (8K) + sB@8192 (32K); Qlds [64][260]@0 (33.3K) overlays;
//      scr@33280 (2K); sWc [256][32]@40960 (16K). total 57344.
__global__ __launch_bounds__(256) void qmsg_kernel(
    const u16* __restrict__ cat, const u16* __restrict__ WqT,
    const float* __restrict__ KSb, const u16* __restrict__ wc,
    const float* __restrict__ g1, const float* __restrict__ b1,
    u16* __restrict__ catout) {
  __shared__ alignas(16) char smem[57344];
  u16* sA = (u16*)smem;
  u16* sB = (u16*)(smem + 8192);
  u16* Qlds = (u16*)smem;
  float* scr = (float*)(smem + 33280);
  u16* sWc = (u16*)(smem + 40960);
  u16* T = (u16*)smem;
  const int t = threadIdx.x;
  const int m0 = blockIdx.x * 64;
  const int b = m0 >> 12;
  const int w = t >> 6, lane = t & 63;
  const int lr = lane & 15, lk = lane >> 4;
  const int wn = w * 64;
  f32x4 acc[4][4] = {};
  float ksv[4];
#pragma unroll
  for (int fn = 0; fn < 4; ++fn) ksv[fn] = KSb[b * 256 + wn + fn * 16 + lr];
  // ---- phase 1: Q-proj GEMM (K=256) ----
  for (int kt = 0; kt < 4; ++kt) {
    __syncthreads();
#pragma unroll
    for (int i = 0; i < 2; ++i) {
      int id = t + i * 256, row = id >> 3, ch = (id & 7) * 8;
      GLDS16(cat + (size_t)(m0 + row) * 512 + kt * 64 + ch, sA + id * 8);
    }
#pragma unroll
    for (int i = 0; i < 8; ++i) {
      int id = t + i * 256, row = id >> 3, ch = (id & 7) * 8;
      GLDS16(WqT + (size_t)row * 256 + kt * 64 + ch, sB + id * 8);
    }
    __syncthreads();
    bf16x8 af[4][2], bfr[4][2];
#pragma unroll
    for (int f = 0; f < 4; ++f)
#pragma unroll
      for (int ks = 0; ks < 2; ++ks) {
        af[f][ks] = *(const bf16x8*)&sA[(f * 16 + lr) * 64 + ks * 32 + lk * 8];
        bfr[f][ks] = *(const bf16x8*)&sB[(wn + f * 16 + lr) * 64 + ks * 32 + lk * 8];
      }
#pragma unroll
    for (int ks = 0; ks < 2; ++ks)
#pragma unroll
      for (int fm = 0; fm < 4; ++fm)
#pragma unroll
        for (int fn = 0; fn < 4; ++fn)
          acc[fm][fn] = __builtin_amdgcn_mfma_f32_16x16x32_bf16(
              af[fm][ks], bfr[fn][ks], acc[fm][fn], 0, 0, 0);
  }
  // ---- elu+1 and per-head z-scale (heads are 32-col aligned in wave tile) ----
#pragma unroll
  for (int fm = 0; fm < 4; ++fm)
#pragma unroll
    for (int r = 0; r < 4; ++r) {
      float q[4];
#pragma unroll
      for (int fn = 0; fn < 4; ++fn) {
        float v = acc[fm][fn][r];
        q[fn] = v > 0.f ? v + 1.f : __expf(v);
      }
      float zd0 = q[0] * ksv[0] + q[1] * ksv[1];
      float zd1 = q[2] * ksv[2] + q[3] * ksv[3];
#pragma unroll
      for (int off = 1; off < 16; off <<= 1) {
        zd0 += __shfl_xor(zd0, off);
        zd1 += __shfl_xor(zd1, off);
      }
      float z0 = 4096.f / (zd0 + 1e-6f);
      float z1 = 4096.f / (zd1 + 1e-6f);
      acc[fm][0][r] = q[0] * z0; acc[fm][1][r] = q[1] * z0;
      acc[fm][2][r] = q[2] * z1; acc[fm][3][r] = q[3] * z1;
    }
  __syncthreads();   // all waves done reading sA/sB -> Qlds overlay safe
#pragma unroll
  for (int fm = 0; fm < 4; ++fm)
#pragma unroll
    for (int fn = 0; fn < 4; ++fn)
#pragma unroll
      for (int r = 0; r < 4; ++r)
        Qlds[(fm * 16 + lk * 4 + r) * 260 + wn + fn * 16 + lr] = f2bf(acc[fm][fn][r]);
  // ---- phase 2: msg = Qs @ Wcomb (K=256 from LDS; B staged BK=32 swizzled) --
  f32x4 acc2[4][4] = {};
  const u16* Bw = wc + (size_t)b * 65536;
  for (int kc = 0; kc < 8; ++kc) {
    __syncthreads();   // kc=0: Qlds writes visible; else: prior sWc reads done
#pragma unroll
    for (int i = 0; i < 4; ++i) {
      int id = t + i * 256, row = id >> 2, ch = (id & 3) * 8;
      GLDS16(Bw + (size_t)row * 256 + kc * 32 + (ch ^ ((row & 3) << 3)), sWc + id * 8);
    }
    __syncthreads();
    bf16x8 a2[4], b2f[4];
#pragma unroll
    for (int f = 0; f < 4; ++f)
      a2[f] = *(const bf16x8*)&Qlds[(f * 16 + lr) * 260 + kc * 32 + lk * 8];
#pragma unroll
    for (int fn = 0; fn < 4; ++fn) {
      int br = wn + fn * 16 + lr;
      b2f[fn] = *(const bf16x8*)&sWc[br * 32 + ((lk * 8) ^ ((br & 3) << 3))];
    }
#pragma unroll
    for (int fm = 0; fm < 4; ++fm)
#pragma unroll
      for (int fn = 0; fn < 4; ++fn)
        acc2[fm][fn] = __builtin_amdgcn_mfma_f32_16x16x32_bf16(
            a2[fm], b2f[fn], acc2[fm][fn], 0, 0, 0);
  }
  // ---- LN1 cross-wave ----
#pragma unroll
  for (int fm = 0; fm < 4; ++fm)
#pragma unroll
    for (int r = 0; r < 4; ++r) {
      float s = 0.f, sq = 0.f;
#pragma unroll
      for (int fn = 0; fn < 4; ++fn) {
        float a = acc2[fm][fn][r];
        s += a; sq += a * a;
      }
#pragma unroll
      for (int off = 1; off < 16; off <<= 1) {
        s += __shfl_xor(s, off);
        sq += __shfl_xor(sq, off);
      }
      if (lr == 0) {
        int row = fm * 16 + lk * 4 + r;
        scr[row * 8 + w * 2] = s;
        scr[row * 8 + w * 2 + 1] = sq;
      }
    }
  __syncthreads();   // also guarantees all Qlds fragment reads are done
  float gvs[4], bvs[4];
#pragma unroll
  for (int fn = 0; fn < 4; ++fn) {
    gvs[fn] = g1[wn + fn * 16 + lr];
    bvs[fn] = b1[wn + fn * 16 + lr];
  }
#pragma unroll
  for (int fm = 0; fm < 4; ++fm)
#pragma unroll
    for (int r = 0; r < 4; ++r) {
      int row = fm * 16 + lk * 4 + r;
      float s = 0.f, sq = 0.f;
#pragma unroll
      for (int j = 0; j < 4; ++j) {
        s += scr[row * 8 + j * 2];
        sq += scr[row * 8 + j * 2 + 1];
      }
      float mu = s * (1.f / 256.f);
      float var = sq * (1.f / 256.f) - mu * mu;
      float rstd = rsqrtf(var + 1e-5f);
#pragma unroll
      for (int fn = 0; fn < 4; ++fn) {
        float y = (acc2[fm][fn][r] - mu) * rstd * gvs[fn] + bvs[fn];
        T[(fm * 16 + lk * 4 + r) * 260 + wn + fn * 16 + lr] = f2bf(y);
      }
    }
  __syncthreads();
  // coalesced bf16 store to cat[:,256:512]
#pragma unroll
  for (int i = 0; i < 8; ++i) {
    int idx = t + i * 256;       // row(6b) x c16(5b)
    int row = idx >> 5, c16 = idx & 31;
    uint4 val = *reinterpret_cast<const uint4*>(&T[row * 260 + c16 * 8]);
    *reinterpret_cast<uint4*>(catout + (size_t)(m0 + row) * 512 + 256 + c16 * 8) = val;
  }
}

// ---- FUSED: MLP1 + relu + MLP2 + LN2 + residual + transpose -> out ----------
// BM=32, 256 threads (4 waves), grid 1024.
// LDS: sX [32][512]@0 (32K, pre-swz src); sW@32768 (16K, W1 tile [128][64] /
//      W2 tile [256][32] swz); sH [32][136]@49152 (8.7K); scr@57856 (1K).
__global__ __launch_bounds__(256) void mlp_fused_kernel(
    const u16* __restrict__ cat, const u16* __restrict__ W1T,
    const u16* __restrict__ W2T, const float* __restrict__ g2,
    const float* __restrict__ b2, float* __restrict__ out) {
  __shared__ alignas(16) char smem[58880];
  u16* sX = (u16*)smem;
  u16* sW = (u16*)(smem + 32768);
  u16* sH = (u16*)(smem + 49152);
  float* scr = (float*)(smem + 57856);
  float* T = (float*)smem;
  const int t = threadIdx.x;
  const int m0 = blockIdx.x * 32;
  const int b = m0 >> 12, l0 = m0 & 4095;
  const int w = t >> 6, lane = t & 63;
  const int lr = lane & 15, lk = lane >> 4;
  const int wn1 = w * 32, wn2 = w * 64;
  // stage A row-block once (source pre-swizzled so reads can de-conflict)
#pragma unroll
  for (int i = 0; i < 8; ++i) {
    int id = t + i * 256;
    int row = id >> 6, ch = (id & 63) * 8;
    GLDS16(cat + (size_t)(m0 + row) * 512 + (ch ^ ((row & 7) << 3)), sX + id * 8);
  }
  f32x4 acc2[2][4] = {};
  for (int nc = 0; nc < 4; ++nc) {
    f32x4 acc1[2][2] = {};
    for (int kc = 0; kc < 8; ++kc) {
      __syncthreads();
#pragma unroll
      for (int i = 0; i < 4; ++i) {
        int id = t + i * 256, row = id >> 3, ch = (id & 7) * 8;
        GLDS16(W1T + (size_t)(nc * 128 + row) * 512 + kc * 64 + ch, sW + id * 8);
      }
      __syncthreads();
      bf16x8 a1[2][2], b1f[2][2];
#pragma unroll
      for (int f = 0; f < 2; ++f)
#pragma unroll
        for (int ks = 0; ks < 2; ++ks) {
          int ar = f * 16 + lr;
          a1[f][ks] = *(const bf16x8*)&sX[ar * 512 +
              ((kc * 64 + ks * 32 + lk * 8) ^ ((ar & 7) << 3))];
          b1f[f][ks] = *(const bf16x8*)&sW[(wn1 + f * 16 + lr) * 64 + ks * 32 + lk * 8];
        }
#pragma unroll
      for (int ks = 0; ks < 2; ++ks)
#pragma unroll
        for (int fm = 0; fm < 2; ++fm)
#pragma unroll
          for (int fn = 0; fn < 2; ++fn)
            acc1[fm][fn] = __builtin_amdgcn_mfma_f32_16x16x32_bf16(
                a1[fm][ks], b1f[fn][ks], acc1[fm][fn], 0, 0, 0);
    }
    // relu -> sH (wave-exclusive columns)
#pragma unroll
    for (int fm = 0; fm < 2; ++fm)
#pragma unroll
      for (int fn = 0; fn < 2; ++fn)
#pragma unroll
        for (int r = 0; r < 4; ++r) {
          float v = acc1[fm][fn][r];
          sH[(fm * 16 + lk * 4 + r) * 136 + wn1 + fn * 16 + lr] =
              f2bf(v > 0.f ? v : 0.f);
        }
    // mlp2 partial-K over this hidden chunk (BK=32, W2 staged swizzled)
    for (int kc2 = 0; kc2 < 4; ++kc2) {
      __syncthreads();  // sH visible (first iter); sW reads done (overwrite)
#pragma unroll
      for (int i = 0; i < 4; ++i) {
        int id = t + i * 256, row = id >> 2, ch = (id & 3) * 8;
        GLDS16(W2T + (size_t)row * 512 + nc * 128 + kc2 * 32 +
                   (ch ^ ((row & 3) << 3)), sW + id * 8);
      }
      __syncthreads();
      bf16x8 a2[2], b2f[4];
#pragma unroll
      for (int f = 0; f < 2; ++f)
        a2[f] = *(const bf16x8*)&sH[(f * 16 + lr) * 136 + kc2 * 32 + lk * 8];
#pragma unroll
      for (int fn = 0; fn < 4; ++fn) {
        int br = wn2 + fn * 16 + lr;
        b2f[fn] = *(const bf16x8*)&sW[br * 32 + ((lk * 8) ^ ((br & 3) << 3))];
      }
#pragma unroll
      for (int fm = 0; fm < 2; ++fm)
#pragma unroll
        for (int fn = 0; fn < 4; ++fn)
          acc2[fm][fn] = __builtin_amdgcn_mfma_f32_16x16x32_bf16(
              a2[fm], b2f[fn], acc2[fm][fn], 0, 0, 0);
    }
  }
  // ---- LN2 cross-wave ----
#pragma unroll
  for (int fm = 0; fm < 2; ++fm)
#pragma unroll
    for (int r = 0; r < 4; ++r) {
      float s = 0.f, sq = 0.f;
#pragma unroll
      for (int fn = 0; fn < 4; ++fn) {
        float a = acc2[fm][fn][r];
        s += a; sq += a * a;
      }
#pragma unroll
      for (int off = 1; off < 16; off <<= 1) {
        s += __shfl_xor(s, off);
        sq += __shfl_xor(sq, off);
      }
      if (lr == 0) {
        int row = fm * 16 + lk * 4 + r;
        scr[row * 8 + w * 2] = s;
        scr[row * 8 + w * 2 + 1] = sq;
      }
    }
  __syncthreads();
  float gvs[4], bvs[4];
#pragma unroll
  for (int fn = 0; fn < 4; ++fn) {
    gvs[fn] = g2[wn2 + fn * 16 + lr];
    bvs[fn] = b2[wn2 + fn * 16 + lr];
  }
#pragma unroll
  for (int fm = 0; fm < 2; ++fm)
#pragma unroll
    for (int r = 0; r < 4; ++r) {
      int row = fm * 16 + lk * 4 + r;
      float s = 0.f, sq = 0.f;
#pragma unroll
      for (int j = 0; j < 4; ++j) {
        s += scr[row * 8 + j * 2];
        sq += scr[row * 8 + j * 2 + 1];
      }
      float mu = s * (1.f / 256.f);
      float var = sq * (1.f / 256.f) - mu * mu;
      float rstd = rsqrtf(var + 1e-5f);
#pragma unroll
      for (int fn = 0; fn < 4; ++fn) {
        float xs = bf2f(cat[(size_t)(m0 + row) * 512 + wn2 + fn * 16 + lr]);
        acc2[fm][fn][r] = (acc2[fm][fn][r] - mu) * rstd * gvs[fn] + bvs[fn] + xs;
      }
    }
  __syncthreads();   // sX dead -> T overlay safe
  // ---- transpose 4 chunks of 64 cols + coalesced f32 store ----
  for (int cc = 0; cc < 4; ++cc) {
    if (w == cc) {
#pragma unroll
      for (int fm = 0; fm < 2; ++fm)
#pragma unroll
        for (int fn = 0; fn < 4; ++fn)
#pragma unroll
          for (int r = 0; r < 4; ++r)
            T[(fn * 16 + lr) * 33 + fm * 16 + lk * 4 + r] = acc2[fm][fn][r];
    }
    __syncthreads();
#pragma unroll
    for (int i = 0; i < 8; ++i) {
      int idx = t + i * 256;
      int cT = idx >> 5, lq = idx & 31;
      out[((size_t)b * 256 + cc * 64 + cT) * 4096 + l0 + lq] = T[cT * 33 + lq];
    }
    __syncthreads();
  }
}

extern "C" void kernel_launch(void* const* d_in, const int* in_sizes, int n_in,
                              void* d_out, int out_size, void* d_ws, size_t ws_size,
                              hipStream_t stream) {
  (void)in_sizes; (void)n_in; (void)out_size; (void)ws_size;
  const float* x = (const float*)d_in[0];
  const float* srcp = (const float*)d_in[1];
  const float* Wq = (const float*)d_in[2];
  const float* Wk = (const float*)d_in[3];
  const float* Wv = (const float*)d_in[4];
  const float* Wm = (const float*)d_in[5];
  const float* W1 = (const float*)d_in[6];
  const float* W2 = (const float*)d_in[7];
  const float* g1 = (const float*)d_in[8];
  const float* b1 = (const float*)d_in[9];
  const float* g2 = (const float*)d_in[10];
  const float* b2 = (const float*)d_in[11];
  float* out = (float*)d_out;
  char* ws = (char*)d_ws;

  u16* wqt = (u16*)(ws + OFF_WQ);
  u16* wkvt = (u16*)(ws + OFF_WK);
  u16* wkt = (u16*)(ws + OFF_WK);
  u16* wvt = (u16*)(ws + OFF_WV);
  u16* wmt = (u16*)(ws + OFF_WM);
  u16* w1t = (u16*)(ws + OFF_W1);
  u16* w2t = (u16*)(ws + OFF_W2);
  u16* cat = (u16*)(ws + OFF_CAT);
  u16* ssb = (u16*)(ws + OFF_SSB);
  u16* kvproj = (u16*)(ws + OFF_KVPROJ);
  float* KVb = (float*)(ws + OFF_KV);
  float* KSb = (float*)(ws + OFF_KS);
  float* KVp = (float*)(ws + OFF_KVP);
  float* KSp = (float*)(ws + OFF_KSP);
  u16* wcombT = (u16*)(ws + OFF_KVP);  // reuse partials after kv_reduce

  dim3 blk(256);
  wprep_all_kernel<<<dim3(640), blk, 0, stream>>>(Wq, Wk, Wv, Wm, W1, W2,
                                                  wqt, wkt, wvt, wmt, w1t, w2t);
  transpose_in_kernel<<<dim3(128, 8, 16), blk, 0, stream>>>(x, srcp, cat, ssb);
  gemm_kernel<4><<<dim3(1024), blk, 0, stream>>>(ssb, 256, wkvt, 256, kvproj, 512);
  kv_partial_kernel<<<dim3(64, 8), blk, 0, stream>>>(kvproj, KVp, KSp);
  kv_reduce_kernel<<<dim3(264), blk, 0, stream>>>(KVp, KSp, KVb, KSb);
  wcomb_kernel<<<dim3(2048), blk, 0, stream>>>(KVb, wmt, wcombT);
  qmsg_kernel<<<dim3(512), blk, 0, stream>>>(cat, wqt, KSb, wcombT, g1, b1, cat);
  mlp_fused_kernel<<<dim3(1024), blk, 0, stream>>>(cat, w1t, w2t, g2, b2, out);
}

// Round 7
// 161.138 us; speedup vs baseline: 1.1580x; 1.1580x over previous
//
#include <hip/hip_runtime.h>

typedef unsigned short u16;
typedef __bf16 bf16x8 __attribute__((ext_vector_type(8)));
typedef float f32x4 __attribute__((ext_vector_type(4)));

__device__ __forceinline__ u16 f2bf(float f) {
  unsigned int u = __float_as_uint(f);
  u += 0x7fffu + ((u >> 16) & 1u);
  return (u16)(u >> 16);
}
__device__ __forceinline__ float bf2f(u16 v) {
  return __uint_as_float(((unsigned)v) << 16);
}

#define GLDS16(gp, lp)                                                   \
  __builtin_amdgcn_global_load_lds(                                      \
      (const __attribute__((address_space(1))) unsigned int*)(gp),       \
      (__attribute__((address_space(3))) unsigned int*)(lp), 16, 0, 0)

// B=8, C=256, L=4096, M=32768, NHEAD=8, dim=32
// ws layout (bytes)
#define OFF_WQ     0u
#define OFF_WK     131072u     /* wkvt rows 0:256 */
#define OFF_WV     262144u
#define OFF_WM     393216u
#define OFF_W1     524288u
#define OFF_W2     1048576u
#define OFF_CAT    1310720u    /* u16 [M][512]: 0:256 xs, 256:512 ln1 */
#define OFF_SSB    34865152u   /* u16 [M][256] ss_bf16 */
#define OFF_KVPROJ 68419584u   /* u16 [M][512] K|vals bf16 ; later hidden */
#define OFF_KV     152305664u  /* f32 [64][32][32] */
#define OFF_KS     152567808u  /* f32 [64][32] */
#define OFF_KVP    152576000u  /* f32 [8][64][32][32] partials ; later wcomb */
#define OFF_KSP    154673152u  /* f32 [8][64][32] partials */

// ---- transposes fp32 [C,L] -> bf16 [L,C] ------------------------------------
__global__ __launch_bounds__(256) void transpose_in_kernel(
    const float* __restrict__ x, const float* __restrict__ srcp,
    u16* __restrict__ cat, u16* __restrict__ ssb) {
  __shared__ float s[32][33];
  int z = blockIdx.z;
  const float* src = z < 8 ? x : srcp;
  u16* dst = z < 8 ? cat : ssb;
  int dstride = z < 8 ? 512 : 256;
  int b = z & 7;
  int lt = blockIdx.x * 32, ct = blockIdx.y * 32;
  int tx = threadIdx.x & 31, ty = threadIdx.x >> 5;
#pragma unroll
  for (int i = 0; i < 4; ++i)
    s[ty + i * 8][tx] = src[((size_t)b * 256 + ct + ty + i * 8) * 4096 + lt + tx];
  __syncthreads();
#pragma unroll
  for (int i = 0; i < 4; ++i)
    dst[((size_t)b * 4096 + lt + ty + i * 8) * dstride + ct + tx] = f2bf(s[tx][ty + i * 8]);
}

// ---- weight prep: fp32 [K,N] -> bf16 [N,K], all weights one dispatch --------
__global__ __launch_bounds__(256) void wprep_all_kernel(
    const float* __restrict__ Wq, const float* __restrict__ Wk,
    const float* __restrict__ Wv, const float* __restrict__ Wm,
    const float* __restrict__ W1, const float* __restrict__ W2,
    u16* __restrict__ dq, u16* __restrict__ dk, u16* __restrict__ dv,
    u16* __restrict__ dm, u16* __restrict__ d1, u16* __restrict__ d2) {
  __shared__ float s[32][33];
  int bid = blockIdx.x;
  const float* src; u16* dst; int Kd, Nd, t;
  if (bid < 64)       { src = Wq; dst = dq; Kd = 256; Nd = 256; t = bid; }
  else if (bid < 128) { src = Wk; dst = dk; Kd = 256; Nd = 256; t = bid - 64; }
  else if (bid < 192) { src = Wv; dst = dv; Kd = 256; Nd = 256; t = bid - 128; }
  else if (bid < 256) { src = Wm; dst = dm; Kd = 256; Nd = 256; t = bid - 192; }
  else if (bid < 512) { src = W1; dst = d1; Kd = 512; Nd = 512; t = bid - 256; }
  else                { src = W2; dst = d2; Kd = 512; Nd = 256; t = bid - 512; }
  int ntn = Nd >> 5;
  int kt = (t / ntn) * 32, nt = (t % ntn) * 32;
  int tx = threadIdx.x & 31, ty = threadIdx.x >> 5;
#pragma unroll
  for (int i = 0; i < 4; ++i)
    s[ty + i * 8][tx] = src[(size_t)(kt + ty + i * 8) * Nd + nt + tx];
  __syncthreads();
#pragma unroll
  for (int i = 0; i < 4; ++i)
    dst[(size_t)(nt + ty + i * 8) * Kd + kt + tx] = f2bf(s[tx][ty + i * 8]);
}

// ---- bf16 MFMA GEMM, 128x256 tile, 8 waves (2m x 4n), gload_lds staging -----
// Grid 512 linear, XCD-chunked (2 n-tiles per m-panel on same XCD).
// EPI: 3 relu bf16 | 4 fused kv (col<256 elu+1, else /4096) bf16
template <int EPI>
__global__ __launch_bounds__(512) void gemm256_kernel(
    const u16* __restrict__ A, int lda, const u16* __restrict__ Wt, int K,
    u16* __restrict__ outp, int ldo) {
  __shared__ alignas(16) u16 sA[128 * 64];
  __shared__ alignas(16) u16 sB[256 * 64];
  const int t = threadIdx.x;
  int bid = blockIdx.x;
  int xcd = bid & 7, i0 = bid >> 3;
  const int m0 = (xcd * 32 + (i0 >> 1)) * 128;
  const int n0 = (i0 & 1) * 256;
  const int w = t >> 6, lane = t & 63;
  const int wm = (w >> 2) * 64, wn = (w & 3) * 64;
  const int lr = lane & 15, lk = lane >> 4;
  f32x4 acc[4][4] = {};
  const int nkt = K >> 6;
  for (int kt = 0; kt < nkt; ++kt) {
    __syncthreads();
#pragma unroll
    for (int i = 0; i < 2; ++i) {
      int id = t + i * 512, row = id >> 3, ch = (id & 7) << 3;
      GLDS16(A + (size_t)(m0 + row) * lda + kt * 64 + ch, sA + id * 8);
    }
#pragma unroll
    for (int i = 0; i < 4; ++i) {
      int id = t + i * 512, row = id >> 3, ch = (id & 7) << 3;
      GLDS16(Wt + (size_t)(n0 + row) * K + kt * 64 + ch, sB + id * 8);
    }
    __syncthreads();
    bf16x8 af[4][2], bfr[4][2];
#pragma unroll
    for (int f = 0; f < 4; ++f) {
#pragma unroll
      for (int ks = 0; ks < 2; ++ks) {
        af[f][ks] = *reinterpret_cast<const bf16x8*>(
            &sA[(wm + f * 16 + lr) * 64 + ks * 32 + lk * 8]);
        bfr[f][ks] = *reinterpret_cast<const bf16x8*>(
            &sB[(wn + f * 16 + lr) * 64 + ks * 32 + lk * 8]);
      }
    }
#pragma unroll
    for (int ks = 0; ks < 2; ++ks)
#pragma unroll
      for (int fm = 0; fm < 4; ++fm)
#pragma unroll
        for (int fn = 0; fn < 4; ++fn)
          acc[fm][fn] = __builtin_amdgcn_mfma_f32_16x16x32_bf16(
              af[fm][ks], bfr[fn][ks], acc[fm][fn], 0, 0, 0);
  }
  const int r0 = (lane >> 4) * 4, c0 = lane & 15;
#pragma unroll
  for (int fm = 0; fm < 4; ++fm) {
#pragma unroll
    for (int fn = 0; fn < 4; ++fn) {
      int gr = m0 + wm + fm * 16 + r0;
      int gc = n0 + wn + fn * 16 + c0;
#pragma unroll
      for (int r = 0; r < 4; ++r) {
        float v = acc[fm][fn][r];
        if (EPI == 3) v = v > 0.f ? v : 0.f;
        if (EPI == 4) v = (gc < 256) ? (v > 0.f ? v + 1.f : __expf(v)) : v * (1.f / 4096.f);
        outp[(size_t)(gr + r) * ldo + gc] = f2bf(v);
      }
    }
  }
}

// ---- KV partial over L-slices (reads bf16 kvproj [M][512]) ------------------
__global__ __launch_bounds__(256) void kv_partial_kernel(
    const u16* __restrict__ KVproj, float* __restrict__ KVp,
    float* __restrict__ KSp) {
  __shared__ alignas(16) float sK[64][32];
  __shared__ alignas(16) float sV[64][32];
  const int bh = blockIdx.x, sl = blockIdx.y;
  const int b = bh >> 3, h = bh & 7;
  const int t = threadIdx.x;
  const int lrow = t >> 2, lcol = (t & 3) * 8;
  const int d = t >> 3, vg = (t & 7) * 4;
  float a0 = 0, a1 = 0, a2 = 0, a3 = 0, ks = 0;
  for (int lt = 0; lt < 512; lt += 64) {
    __syncthreads();
    size_t roff = ((size_t)b * 4096 + sl * 512 + lt + lrow) * 512 + h * 32 + lcol;
    uint4 kq = *reinterpret_cast<const uint4*>(KVproj + roff);
    uint4 vq = *reinterpret_cast<const uint4*>(KVproj + roff + 256);
    float* dk = &sK[lrow][lcol];
    float* dv = &sV[lrow][lcol];
#pragma unroll
    for (int j = 0; j < 4; ++j) {
      unsigned uk = ((const unsigned*)&kq)[j];
      unsigned uv = ((const unsigned*)&vq)[j];
      dk[2 * j] = __uint_as_float(uk << 16);
      dk[2 * j + 1] = __uint_as_float(uk & 0xffff0000u);
      dv[2 * j] = __uint_as_float(uv << 16);
      dv[2 * j + 1] = __uint_as_float(uv & 0xffff0000u);
    }
    __syncthreads();
#pragma unroll 8
    for (int i = 0; i < 64; ++i) {
      float kd = sK[i][d];
      a0 += kd * sV[i][vg + 0];
      a1 += kd * sV[i][vg + 1];
      a2 += kd * sV[i][vg + 2];
      a3 += kd * sV[i][vg + 3];
      ks += kd;
    }
  }
  float* o = KVp + (size_t)sl * 65536 + bh * 1024 + d * 32 + vg;
  o[0] = a0; o[1] = a1; o[2] = a2; o[3] = a3;
  if ((t & 7) == 0) KSp[(size_t)sl * 2048 + bh * 32 + d] = ks;
}

__global__ __launch_bounds__(256) void kv_reduce_kernel(
    const float* __restrict__ KVp, const float* __restrict__ KSp,
    float* __restrict__ KV, float* __restrict__ Ksum) {
  int gid = blockIdx.x * 256 + threadIdx.x;
  if (gid < 65536) {
    float s = 0;
#pragma unroll
    for (int i = 0; i < 8; ++i) s += KVp[(size_t)i * 65536 + gid];
    KV[gid] = s;
  } else if (gid - 65536 < 2048) {
    int j = gid - 65536;
    float s = 0;
#pragma unroll
    for (int i = 0; i < 8; ++i) s += KSp[(size_t)i * 2048 + j];
    Ksum[j] = s;
  }
}

// ---- W_comb[b][n][k] = sum_v KV[b,h(k),d(k),v] * WmT[n][h*32+v] -> bf16 -----
__global__ __launch_bounds__(256) void wcomb_kernel(
    const float* __restrict__ KVb, const u16* __restrict__ wmt,
    u16* __restrict__ wc) {
  const int bid = blockIdx.x;  // 0..2047
  const int b = bid >> 8, n = bid & 255;
  const int k = threadIdx.x, h = k >> 5, d = k & 31;
  const float* kv = KVb + ((size_t)b * 8 + h) * 1024 + d * 32;
  const u16* wm = wmt + (size_t)n * 256 + h * 32;
  float s = 0.f;
#pragma unroll
  for (int v = 0; v < 32; ++v) s += kv[v] * bf2f(wm[v]);
  wc[((size_t)b * 256 + n) * 256 + k] = f2bf(s);
}

// ---- FUSED: Qproj + elu+1 + z-scale + (Qs @ Wcomb) + LN1 -> cat[:,256:512] --
// BM=64, 256 threads (4 waves, 1m x 4n), grid 512.
__global__ __launch_bounds__(256) void qmsg_kernel(
    const u16* __restrict__ cat, const u16* __restrict__ WqT,
    const float* __restrict__ KSb, const u16* __restrict__ wc,
    const float* __restrict__ g1, const float* __restrict__ b1,
    u16* __restrict__ catout) {
  __shared__ alignas(16) char smem[57344];
  u16* sA = (u16*)smem;
  u16* sB = (u16*)(smem + 8192);
  u16* Qlds = (u16*)smem;
  float* scr = (float*)(smem + 33280);
  u16* sWc = (u16*)(smem + 40960);
  u16* T = (u16*)smem;
  const int t = threadIdx.x;
  const int m0 = blockIdx.x * 64;
  const int b = m0 >> 12;
  const int w = t >> 6, lane = t & 63;
  const int lr = lane & 15, lk = lane >> 4;
  const int wn = w * 64;
  f32x4 acc[4][4] = {};
  float ksv[4];
#pragma unroll
  for (int fn = 0; fn < 4; ++fn) ksv[fn] = KSb[b * 256 + wn + fn * 16 + lr];
  // ---- phase 1: Q-proj GEMM (K=256) ----
  for (int kt = 0; kt < 4; ++kt) {
    __syncthreads();
#pragma unroll
    for (int i = 0; i < 2; ++i) {
      int id = t + i * 256, row = id >> 3, ch = (id & 7) * 8;
      GLDS16(cat + (size_t)(m0 + row) * 512 + kt * 64 + ch, sA + id * 8);
    }
#pragma unroll
    for (int i = 0; i < 8; ++i) {
      int id = t + i * 256, row = id >> 3, ch = (id & 7) * 8;
      GLDS16(WqT + (size_t)row * 256 + kt * 64 + ch, sB + id * 8);
    }
    __syncthreads();
    bf16x8 af[4][2], bfr[4][2];
#pragma unroll
    for (int f = 0; f < 4; ++f)
#pragma unroll
      for (int ks = 0; ks < 2; ++ks) {
        af[f][ks] = *(const bf16x8*)&sA[(f * 16 + lr) * 64 + ks * 32 + lk * 8];
        bfr[f][ks] = *(const bf16x8*)&sB[(wn + f * 16 + lr) * 64 + ks * 32 + lk * 8];
      }
#pragma unroll
    for (int ks = 0; ks < 2; ++ks)
#pragma unroll
      for (int fm = 0; fm < 4; ++fm)
#pragma unroll
        for (int fn = 0; fn < 4; ++fn)
          acc[fm][fn] = __builtin_amdgcn_mfma_f32_16x16x32_bf16(
              af[fm][ks], bfr[fn][ks], acc[fm][fn], 0, 0, 0);
  }
  // ---- elu+1 and per-head z-scale ----
#pragma unroll
  for (int fm = 0; fm < 4; ++fm)
#pragma unroll
    for (int r = 0; r < 4; ++r) {
      float q[4];
#pragma unroll
      for (int fn = 0; fn < 4; ++fn) {
        float v = acc[fm][fn][r];
        q[fn] = v > 0.f ? v + 1.f : __expf(v);
      }
      float zd0 = q[0] * ksv[0] + q[1] * ksv[1];
      float zd1 = q[2] * ksv[2] + q[3] * ksv[3];
#pragma unroll
      for (int off = 1; off < 16; off <<= 1) {
        zd0 += __shfl_xor(zd0, off);
        zd1 += __shfl_xor(zd1, off);
      }
      float z0 = 4096.f / (zd0 + 1e-6f);
      float z1 = 4096.f / (zd1 + 1e-6f);
      acc[fm][0][r] = q[0] * z0; acc[fm][1][r] = q[1] * z0;
      acc[fm][2][r] = q[2] * z1; acc[fm][3][r] = q[3] * z1;
    }
  __syncthreads();
#pragma unroll
  for (int fm = 0; fm < 4; ++fm)
#pragma unroll
    for (int fn = 0; fn < 4; ++fn)
#pragma unroll
      for (int r = 0; r < 4; ++r)
        Qlds[(fm * 16 + lk * 4 + r) * 260 + wn + fn * 16 + lr] = f2bf(acc[fm][fn][r]);
  // ---- phase 2: msg = Qs @ Wcomb ----
  f32x4 acc2[4][4] = {};
  const u16* Bw = wc + (size_t)b * 65536;
  for (int kc = 0; kc < 8; ++kc) {
    __syncthreads();
#pragma unroll
    for (int i = 0; i < 4; ++i) {
      int id = t + i * 256, row = id >> 2, ch = (id & 3) * 8;
      GLDS16(Bw + (size_t)row * 256 + kc * 32 + (ch ^ ((row & 3) << 3)), sWc + id * 8);
    }
    __syncthreads();
    bf16x8 a2[4], b2f[4];
#pragma unroll
    for (int f = 0; f < 4; ++f)
      a2[f] = *(const bf16x8*)&Qlds[(f * 16 + lr) * 260 + kc * 32 + lk * 8];
#pragma unroll
    for (int fn = 0; fn < 4; ++fn) {
      int br = wn + fn * 16 + lr;
      b2f[fn] = *(const bf16x8*)&sWc[br * 32 + ((lk * 8) ^ ((br & 3) << 3))];
    }
#pragma unroll
    for (int fm = 0; fm < 4; ++fm)
#pragma unroll
      for (int fn = 0; fn < 4; ++fn)
        acc2[fm][fn] = __builtin_amdgcn_mfma_f32_16x16x32_bf16(
            a2[fm], b2f[fn], acc2[fm][fn], 0, 0, 0);
  }
  // ---- LN1 cross-wave ----
#pragma unroll
  for (int fm = 0; fm < 4; ++fm)
#pragma unroll
    for (int r = 0; r < 4; ++r) {
      float s = 0.f, sq = 0.f;
#pragma unroll
      for (int fn = 0; fn < 4; ++fn) {
        float a = acc2[fm][fn][r];
        s += a; sq += a * a;
      }
#pragma unroll
      for (int off = 1; off < 16; off <<= 1) {
        s += __shfl_xor(s, off);
        sq += __shfl_xor(sq, off);
      }
      if (lr == 0) {
        int row = fm * 16 + lk * 4 + r;
        scr[row * 8 + w * 2] = s;
        scr[row * 8 + w * 2 + 1] = sq;
      }
    }
  __syncthreads();
  float gvs[4], bvs[4];
#pragma unroll
  for (int fn = 0; fn < 4; ++fn) {
    gvs[fn] = g1[wn + fn * 16 + lr];
    bvs[fn] = b1[wn + fn * 16 + lr];
  }
#pragma unroll
  for (int fm = 0; fm < 4; ++fm)
#pragma unroll
    for (int r = 0; r < 4; ++r) {
      int row = fm * 16 + lk * 4 + r;
      float s = 0.f, sq = 0.f;
#pragma unroll
      for (int j = 0; j < 4; ++j) {
        s += scr[row * 8 + j * 2];
        sq += scr[row * 8 + j * 2 + 1];
      }
      float mu = s * (1.f / 256.f);
      float var = sq * (1.f / 256.f) - mu * mu;
      float rstd = rsqrtf(var + 1e-5f);
#pragma unroll
      for (int fn = 0; fn < 4; ++fn) {
        float y = (acc2[fm][fn][r] - mu) * rstd * gvs[fn] + bvs[fn];
        T[(fm * 16 + lk * 4 + r) * 260 + wn + fn * 16 + lr] = f2bf(y);
      }
    }
  __syncthreads();
#pragma unroll
  for (int i = 0; i < 8; ++i) {
    int idx = t + i * 256;
    int row = idx >> 5, c16 = idx & 31;
    uint4 val = *reinterpret_cast<const uint4*>(&T[row * 260 + c16 * 8]);
    *reinterpret_cast<uint4*>(catout + (size_t)(m0 + row) * 512 + 256 + c16 * 8) = val;
  }
}

// ---- FUSED: MLP2 + LN2 + bf16-residual + transpose -> out -------------------
__global__ __launch_bounds__(512) void mlp2_tail_kernel(
    const u16* __restrict__ hidden, const u16* __restrict__ W2T,
    const float* __restrict__ g2, const float* __restrict__ b2,
    const u16* __restrict__ catp, float* __restrict__ out) {
  __shared__ alignas(16) char smem[16384 + 32768 + 4096 + 2048];
  u16* sA = (u16*)smem;                   // [128][64]
  u16* sB = (u16*)(smem + 16384);         // [256][64]
  float* scr = (float*)(smem + 49152);    // [128][8]
  float* sG = (float*)(smem + 53248);     // g2|b2
  float* T = (float*)smem;                // [64][129] overlay, post-GEMM
  const int t = threadIdx.x;
  const int m0 = blockIdx.x * 128;
  const int b = m0 >> 12, l0 = m0 & 4095;
  if (t < 256) { sG[t] = g2[t]; sG[256 + t] = b2[t]; }
  const int w = t >> 6, lane = t & 63;
  const int wm = (w >> 2) * 64, wn = (w & 3) * 64;
  const int lr = lane & 15, lk = lane >> 4;
  f32x4 acc[4][4] = {};
  for (int kt = 0; kt < 8; ++kt) {
    __syncthreads();
#pragma unroll
    for (int i = 0; i < 2; ++i) {
      int id = t + i * 512, row = id >> 3, chn = (id & 7) << 3;
      GLDS16(hidden + (size_t)(m0 + row) * 512 + kt * 64 + chn, sA + id * 8);
    }
#pragma unroll
    for (int i = 0; i < 4; ++i) {
      int id = t + i * 512, row = id >> 3, chn = (id & 7) << 3;
      GLDS16(W2T + (size_t)row * 512 + kt * 64 + chn, sB + id * 8);
    }
    __syncthreads();
    bf16x8 af[4][2], bfr[4][2];
#pragma unroll
    for (int f = 0; f < 4; ++f) {
#pragma unroll
      for (int ks = 0; ks < 2; ++ks) {
        af[f][ks] = *reinterpret_cast<const bf16x8*>(
            &sA[(wm + f * 16 + lr) * 64 + ks * 32 + lk * 8]);
        bfr[f][ks] = *reinterpret_cast<const bf16x8*>(
            &sB[(wn + f * 16 + lr) * 64 + ks * 32 + lk * 8]);
      }
    }
#pragma unroll
    for (int ks = 0; ks < 2; ++ks)
#pragma unroll
      for (int fm = 0; fm < 4; ++fm)
#pragma unroll
        for (int fn = 0; fn < 4; ++fn)
          acc[fm][fn] = __builtin_amdgcn_mfma_f32_16x16x32_bf16(
              af[fm][ks], bfr[fn][ks], acc[fm][fn], 0, 0, 0);
  }
  // ---- LN2 cross-wave ----
#pragma unroll
  for (int fm = 0; fm < 4; ++fm)
#pragma unroll
    for (int r = 0; r < 4; ++r) {
      float s = 0.f, sq = 0.f;
#pragma unroll
      for (int fn = 0; fn < 4; ++fn) {
        float a = acc[fm][fn][r];
        s += a; sq += a * a;
      }
#pragma unroll
      for (int off = 1; off < 16; off <<= 1) {
        s += __shfl_xor(s, off);
        sq += __shfl_xor(sq, off);
      }
      if (lr == 0) {
        int row = wm + fm * 16 + lk * 4 + r;
        scr[row * 8 + (w & 3) * 2] = s;
        scr[row * 8 + (w & 3) * 2 + 1] = sq;
      }
    }
  __syncthreads();
  float gvs[4], bvs[4];
#pragma unroll
  for (int fn = 0; fn < 4; ++fn) {
    gvs[fn] = sG[wn + fn * 16 + lr];
    bvs[fn] = sG[256 + wn + fn * 16 + lr];
  }
#pragma unroll
  for (int fm = 0; fm < 4; ++fm)
#pragma unroll
    for (int r = 0; r < 4; ++r) {
      int row = wm + fm * 16 + lk * 4 + r;
      float s = 0.f, sq = 0.f;
#pragma unroll
      for (int j = 0; j < 4; ++j) {
        s += scr[row * 8 + j * 2];
        sq += scr[row * 8 + j * 2 + 1];
      }
      float mu = s * (1.f / 256.f);
      float var = sq * (1.f / 256.f) - mu * mu;
      float rstd = rsqrtf(var + 1e-5f);
#pragma unroll
      for (int fn = 0; fn < 4; ++fn) {
        float xs = bf2f(catp[(size_t)(m0 + row) * 512 + wn + fn * 16 + lr]);
        acc[fm][fn][r] = (acc[fm][fn][r] - mu) * rstd * gvs[fn] + bvs[fn] + xs;
      }
    }
  __syncthreads();
  // ---- transpose chunks of 64 cols, coalesced f32 write ----
  for (int cc = 0; cc < 4; ++cc) {
    if ((w & 3) == cc) {
#pragma unroll
      for (int fm = 0; fm < 4; ++fm)
#pragma unroll
        for (int fn = 0; fn < 4; ++fn)
#pragma unroll
          for (int r = 0; r < 4; ++r)
            T[(fn * 16 + lr) * 129 + wm + fm * 16 + lk * 4 + r] = acc[fm][fn][r];
    }
    __syncthreads();
#pragma unroll
    for (int i = 0; i < 4; ++i) {
      int idx = t + i * 512;
      int cT = idx >> 5, lq = (idx & 31) * 4;
      int cg = cc * 64 + cT;
      size_t o = ((size_t)b * 256 + cg) * 4096 + l0 + lq;
      float4 ov;
      ov.x = T[cT * 129 + lq];
      ov.y = T[cT * 129 + lq + 1];
      ov.z = T[cT * 129 + lq + 2];
      ov.w = T[cT * 129 + lq + 3];
      *reinterpret_cast<float4*>(out + o) = ov;
    }
    __syncthreads();
  }
}

extern "C" void kernel_launch(void* const* d_in, const int* in_sizes, int n_in,
                              void* d_out, int out_size, void* d_ws, size_t ws_size,
                              hipStream_t stream) {
  (void)in_sizes; (void)n_in; (void)out_size; (void)ws_size;
  const float* x = (const float*)d_in[0];
  const float* srcp = (const float*)d_in[1];
  const float* Wq = (const float*)d_in[2];
  const float* Wk = (const float*)d_in[3];
  const float* Wv = (const float*)d_in[4];
  const float* Wm = (const float*)d_in[5];
  const float* W1 = (const float*)d_in[6];
  const float* W2 = (const float*)d_in[7];
  const float* g1 = (const float*)d_in[8];
  const float* b1 = (const float*)d_in[9];
  const float* g2 = (const float*)d_in[10];
  const float* b2 = (const float*)d_in[11];
  float* out = (float*)d_out;
  char* ws = (char*)d_ws;

  u16* wqt = (u16*)(ws + OFF_WQ);
  u16* wkvt = (u16*)(ws + OFF_WK);
  u16* wkt = (u16*)(ws + OFF_WK);
  u16* wvt = (u16*)(ws + OFF_WV);
  u16* wmt = (u16*)(ws + OFF_WM);
  u16* w1t = (u16*)(ws + OFF_W1);
  u16* w2t = (u16*)(ws + OFF_W2);
  u16* cat = (u16*)(ws + OFF_CAT);
  u16* ssb = (u16*)(ws + OFF_SSB);
  u16* kvproj = (u16*)(ws + OFF_KVPROJ);
  float* KVb = (float*)(ws + OFF_KV);
  float* KSb = (float*)(ws + OFF_KS);
  float* KVp = (float*)(ws + OFF_KVP);
  float* KSp = (float*)(ws + OFF_KSP);
  u16* hidden = kvproj;                // reuse after kv_partial consumed kvproj
  u16* wcombT = (u16*)(ws + OFF_KVP);  // reuse partials after kv_reduce

  dim3 blk(256);
  wprep_all_kernel<<<dim3(640), blk, 0, stream>>>(Wq, Wk, Wv, Wm, W1, W2,
                                                  wqt, wkt, wvt, wmt, w1t, w2t);
  transpose_in_kernel<<<dim3(128, 8, 16), blk, 0, stream>>>(x, srcp, cat, ssb);
  gemm256_kernel<4><<<dim3(512), dim3(512), 0, stream>>>(ssb, 256, wkvt, 256, kvproj, 512);
  kv_partial_kernel<<<dim3(64, 8), blk, 0, stream>>>(kvproj, KVp, KSp);
  kv_reduce_kernel<<<dim3(264), blk, 0, stream>>>(KVp, KSp, KVb, KSb);
  wcomb_kernel<<<dim3(2048), blk, 0, stream>>>(KVb, wmt, wcombT);
  qmsg_kernel<<<dim3(512), blk, 0, stream>>>(cat, wqt, KSb, wcombT, g1, b1, cat);
  gemm256_kernel<3><<<dim3(512), dim3(512), 0, stream>>>(cat, 512, w1t, 512, hidden, 512);
  mlp2_tail_kernel<<<dim3(256), dim3(512), 0, stream>>>(hidden, w2t, g2, b2, cat, out);
}

// Round 8
// 158.572 us; speedup vs baseline: 1.1768x; 1.0162x over previous
//
#include <hip/hip_runtime.h>

typedef unsigned short u16;
typedef __bf16 bf16x8 __attribute__((ext_vector_type(8)));
typedef float f32x4 __attribute__((ext_vector_type(4)));

__device__ __forceinline__ u16 f2bf(float f) {
  unsigned int u = __float_as_uint(f);
  u += 0x7fffu + ((u >> 16) & 1u);
  return (u16)(u >> 16);
}
__device__ __forceinline__ float bf2f(u16 v) {
  return __uint_as_float(((unsigned)v) << 16);
}

#define GLDS16(gp, lp)                                                   \
  __builtin_amdgcn_global_load_lds(                                      \
      (const __attribute__((address_space(1))) unsigned int*)(gp),       \
      (__attribute__((address_space(3))) unsigned int*)(lp), 16, 0, 0)

// B=8, C=256, L=4096, M=32768, NHEAD=8, dim=32
// ws layout (bytes)
#define OFF_WQ     0u
#define OFF_WK     131072u     /* wkvt rows 0:256 */
#define OFF_WV     262144u
#define OFF_WM     393216u
#define OFF_W1     524288u
#define OFF_W2     1048576u
#define OFF_CAT    1310720u    /* u16 [M][512]: 0:256 xs, 256:512 ln1 */
#define OFF_SSB    34865152u   /* u16 [M][256] ss_bf16 */
#define OFF_KVPROJ 68419584u   /* u16 [M][512] K|vals bf16 ; later hidden */
#define OFF_KS     152567808u  /* f32 [64][32] Ksum */
#define OFF_KVP    152576000u  /* f32 [8][64][32][32] partials */
#define OFF_KSP    154673152u  /* f32 [8][64][32] partials */
#define OFF_WC     154740736u  /* u16 [8][256][256] wcomb (no alias w/ KVP) */

// ---- transpose fp32 [C,L] -> bf16 [L,C], 64x64 tiles, uint4 writes ----------
__global__ __launch_bounds__(256) void transpose_in_kernel(
    const float* __restrict__ x, const float* __restrict__ srcp,
    u16* __restrict__ cat, u16* __restrict__ ssb) {
  __shared__ float s[64][65];
  const int z = blockIdx.z;
  const float* src = z < 8 ? x : srcp;
  u16* dst = z < 8 ? cat : ssb;
  const int dstride = z < 8 ? 512 : 256;
  const int b = z & 7;
  const int lt = blockIdx.x * 64, ct = blockIdx.y * 64;
  const int t = threadIdx.x;
  const int cl = t >> 2, loff = (t & 3) * 16;
#pragma unroll
  for (int j = 0; j < 4; ++j) {
    float4 v = *reinterpret_cast<const float4*>(
        src + ((size_t)b * 256 + ct + cl) * 4096 + lt + loff + j * 4);
    s[cl][loff + j * 4 + 0] = v.x;
    s[cl][loff + j * 4 + 1] = v.y;
    s[cl][loff + j * 4 + 2] = v.z;
    s[cl][loff + j * 4 + 3] = v.w;
  }
  __syncthreads();
#pragma unroll
  for (int i = 0; i < 2; ++i) {
    int id = t + i * 256;          // 0..511
    int ll = id >> 3, cg = id & 7;
    unsigned pk[4];
#pragma unroll
    for (int j = 0; j < 4; ++j) {
      unsigned lo = f2bf(s[cg * 8 + j * 2][ll]);
      unsigned hi = f2bf(s[cg * 8 + j * 2 + 1][ll]);
      pk[j] = lo | (hi << 16);
    }
    uint4 val = {pk[0], pk[1], pk[2], pk[3]};
    *reinterpret_cast<uint4*>(
        dst + ((size_t)b * 4096 + lt + ll) * dstride + ct + cg * 8) = val;
  }
}

// ---- weight prep: fp32 [K,N] -> bf16 [N,K], all weights one dispatch --------
__global__ __launch_bounds__(256) void wprep_all_kernel(
    const float* __restrict__ Wq, const float* __restrict__ Wk,
    const float* __restrict__ Wv, const float* __restrict__ Wm,
    const float* __restrict__ W1, const float* __restrict__ W2,
    u16* __restrict__ dq, u16* __restrict__ dk, u16* __restrict__ dv,
    u16* __restrict__ dm, u16* __restrict__ d1, u16* __restrict__ d2) {
  __shared__ float s[32][33];
  int bid = blockIdx.x;
  const float* src; u16* dst; int Kd, Nd, t;
  if (bid < 64)       { src = Wq; dst = dq; Kd = 256; Nd = 256; t = bid; }
  else if (bid < 128) { src = Wk; dst = dk; Kd = 256; Nd = 256; t = bid - 64; }
  else if (bid < 192) { src = Wv; dst = dv; Kd = 256; Nd = 256; t = bid - 128; }
  else if (bid < 256) { src = Wm; dst = dm; Kd = 256; Nd = 256; t = bid - 192; }
  else if (bid < 512) { src = W1; dst = d1; Kd = 512; Nd = 512; t = bid - 256; }
  else                { src = W2; dst = d2; Kd = 512; Nd = 256; t = bid - 512; }
  int ntn = Nd >> 5;
  int kt = (t / ntn) * 32, nt = (t % ntn) * 32;
  int tx = threadIdx.x & 31, ty = threadIdx.x >> 5;
#pragma unroll
  for (int i = 0; i < 4; ++i)
    s[ty + i * 8][tx] = src[(size_t)(kt + ty + i * 8) * Nd + nt + tx];
  __syncthreads();
#pragma unroll
  for (int i = 0; i < 4; ++i)
    dst[(size_t)(nt + ty + i * 8) * Kd + kt + tx] = f2bf(s[tx][ty + i * 8]);
}

// ---- bf16 MFMA GEMM, 128x256 tile, 8 waves (2m x 4n), gload_lds staging -----
// Grid 512 linear, XCD-chunked. EPI: 3 relu bf16 | 4 fused kv bf16
template <int EPI>
__global__ __launch_bounds__(512) void gemm256_kernel(
    const u16* __restrict__ A, int lda, const u16* __restrict__ Wt, int K,
    u16* __restrict__ outp, int ldo) {
  __shared__ alignas(16) u16 sA[128 * 64];
  __shared__ alignas(16) u16 sB[256 * 64];
  const int t = threadIdx.x;
  int bid = blockIdx.x;
  int xcd = bid & 7, i0 = bid >> 3;
  const int m0 = (xcd * 32 + (i0 >> 1)) * 128;
  const int n0 = (i0 & 1) * 256;
  const int w = t >> 6, lane = t & 63;
  const int wm = (w >> 2) * 64, wn = (w & 3) * 64;
  const int lr = lane & 15, lk = lane >> 4;
  f32x4 acc[4][4] = {};
  const int nkt = K >> 6;
  for (int kt = 0; kt < nkt; ++kt) {
    __syncthreads();
#pragma unroll
    for (int i = 0; i < 2; ++i) {
      int id = t + i * 512, row = id >> 3, ch = (id & 7) << 3;
      GLDS16(A + (size_t)(m0 + row) * lda + kt * 64 + ch, sA + id * 8);
    }
#pragma unroll
    for (int i = 0; i < 4; ++i) {
      int id = t + i * 512, row = id >> 3, ch = (id & 7) << 3;
      GLDS16(Wt + (size_t)(n0 + row) * K + kt * 64 + ch, sB + id * 8);
    }
    __syncthreads();
    bf16x8 af[4][2], bfr[4][2];
#pragma unroll
    for (int f = 0; f < 4; ++f) {
#pragma unroll
      for (int ks = 0; ks < 2; ++ks) {
        af[f][ks] = *reinterpret_cast<const bf16x8*>(
            &sA[(wm + f * 16 + lr) * 64 + ks * 32 + lk * 8]);
        bfr[f][ks] = *reinterpret_cast<const bf16x8*>(
            &sB[(wn + f * 16 + lr) * 64 + ks * 32 + lk * 8]);
      }
    }
#pragma unroll
    for (int ks = 0; ks < 2; ++ks)
#pragma unroll
      for (int fm = 0; fm < 4; ++fm)
#pragma unroll
        for (int fn = 0; fn < 4; ++fn)
          acc[fm][fn] = __builtin_amdgcn_mfma_f32_16x16x32_bf16(
              af[fm][ks], bfr[fn][ks], acc[fm][fn], 0, 0, 0);
  }
  const int r0 = (lane >> 4) * 4, c0 = lane & 15;
#pragma unroll
  for (int fm = 0; fm < 4; ++fm) {
#pragma unroll
    for (int fn = 0; fn < 4; ++fn) {
      int gr = m0 + wm + fm * 16 + r0;
      int gc = n0 + wn + fn * 16 + c0;
#pragma unroll
      for (int r = 0; r < 4; ++r) {
        float v = acc[fm][fn][r];
        if (EPI == 3) v = v > 0.f ? v : 0.f;
        if (EPI == 4) v = (gc < 256) ? (v > 0.f ? v + 1.f : __expf(v)) : v * (1.f / 4096.f);
        outp[(size_t)(gr + r) * ldo + gc] = f2bf(v);
      }
    }
  }
}

// ---- KV partial over L-slices (reads bf16 kvproj [M][512]) ------------------
__global__ __launch_bounds__(256) void kv_partial_kernel(
    const u16* __restrict__ KVproj, float* __restrict__ KVp,
    float* __restrict__ KSp) {
  __shared__ alignas(16) float sK[64][32];
  __shared__ alignas(16) float sV[64][32];
  const int bh = blockIdx.x, sl = blockIdx.y;
  const int b = bh >> 3, h = bh & 7;
  const int t = threadIdx.x;
  const int lrow = t >> 2, lcol = (t & 3) * 8;
  const int d = t >> 3, vg = (t & 7) * 4;
  float a0 = 0, a1 = 0, a2 = 0, a3 = 0, ks = 0;
  for (int lt = 0; lt < 512; lt += 64) {
    __syncthreads();
    size_t roff = ((size_t)b * 4096 + sl * 512 + lt + lrow) * 512 + h * 32 + lcol;
    uint4 kq = *reinterpret_cast<const uint4*>(KVproj + roff);
    uint4 vq = *reinterpret_cast<const uint4*>(KVproj + roff + 256);
    float* dk = &sK[lrow][lcol];
    float* dv = &sV[lrow][lcol];
#pragma unroll
    for (int j = 0; j < 4; ++j) {
      unsigned uk = ((const unsigned*)&kq)[j];
      unsigned uv = ((const unsigned*)&vq)[j];
      dk[2 * j] = __uint_as_float(uk << 16);
      dk[2 * j + 1] = __uint_as_float(uk & 0xffff0000u);
      dv[2 * j] = __uint_as_float(uv << 16);
      dv[2 * j + 1] = __uint_as_float(uv & 0xffff0000u);
    }
    __syncthreads();
#pragma unroll 8
    for (int i = 0; i < 64; ++i) {
      float kd = sK[i][d];
      a0 += kd * sV[i][vg + 0];
      a1 += kd * sV[i][vg + 1];
      a2 += kd * sV[i][vg + 2];
      a3 += kd * sV[i][vg + 3];
      ks += kd;
    }
  }
  float* o = KVp + (size_t)sl * 65536 + bh * 1024 + d * 32 + vg;
  o[0] = a0; o[1] = a1; o[2] = a2; o[3] = a3;
  if ((t & 7) == 0) KSp[(size_t)sl * 2048 + bh * 32 + d] = ks;
}

// ---- merged: reduce KVp -> KV[b] (LDS) ; Ksum ; wcomb chunk -----------------
// grid 64 = (b, nc); wc[b][n][k] = sum_v KV[b,h(k),d(k),v]*wmT[n][h*32+v]
__global__ __launch_bounds__(256) void kvred_wcomb_kernel(
    const float* __restrict__ KVp, const float* __restrict__ KSp,
    const u16* __restrict__ wmt, u16* __restrict__ wc,
    float* __restrict__ Ksum) {
  __shared__ float sKV[8 * 1032];
  const int b = blockIdx.x >> 3, nc = blockIdx.x & 7;
  const int t = threadIdx.x;
#pragma unroll
  for (int i = 0; i < 32; ++i) {
    int idx = t + i * 256;               // 0..8191 = h*1024 + rest
    float s = 0.f;
#pragma unroll
    for (int sl = 0; sl < 8; ++sl) s += KVp[(size_t)sl * 65536 + b * 8192 + idx];
    sKV[(idx >> 10) * 1032 + (idx & 1023)] = s;
  }
  if (nc == 0) {
    float s = 0.f;
#pragma unroll
    for (int sl = 0; sl < 8; ++sl) s += KSp[(size_t)sl * 2048 + b * 256 + t];
    Ksum[b * 256 + t] = s;
  }
  __syncthreads();
  const int n = nc * 32 + (t >> 3), h = t & 7;
  float wmv[32];
  const u16* wmrow = wmt + (size_t)n * 256 + h * 32;
#pragma unroll
  for (int v = 0; v < 32; ++v) wmv[v] = bf2f(wmrow[v]);
  unsigned pk[16];
  const float* kvh = &sKV[h * 1032];
#pragma unroll
  for (int dp = 0; dp < 16; ++dp) {
    unsigned lohi[2];
#pragma unroll
    for (int e = 0; e < 2; ++e) {
      int d = dp * 2 + e;
      const float* kv = kvh + d * 32;
      float s = 0.f;
#pragma unroll
      for (int v = 0; v < 32; ++v) s += kv[v] * wmv[v];
      lohi[e] = f2bf(s);
    }
    pk[dp] = lohi[0] | (lohi[1] << 16);
  }
  uint4* dst = (uint4*)(wc + ((size_t)b * 256 + n) * 256 + h * 32);
#pragma unroll
  for (int j = 0; j < 4; ++j) {
    uint4 val = {pk[j * 4], pk[j * 4 + 1], pk[j * 4 + 2], pk[j * 4 + 3]};
    dst[j] = val;
  }
}

// ---- FUSED: Qproj + elu+1 + z-scale + (Qs @ Wcomb) + LN1 -> cat[:,256:512] --
// BM=128, 512 threads (8 waves 2m x 4n), grid 256.
// LDS: phase1 sA[128][64]@0 + sB[256][64]@16384; then Qlds[128][136]@0 overlay
//      (one 128-col K-half of Qs at a time); sWc[256][32]@35840; scr@52224.
__global__ __launch_bounds__(512) void qmsg_kernel(
    const u16* __restrict__ cat, const u16* __restrict__ WqT,
    const float* __restrict__ KSb, const u16* __restrict__ wc,
    const float* __restrict__ g1, const float* __restrict__ b1,
    u16* __restrict__ catout) {
  __shared__ alignas(16) char smem[57344];
  u16* sA = (u16*)smem;
  u16* sB = (u16*)(smem + 16384);
  u16* Qlds = (u16*)smem;
  u16* sWc = (u16*)(smem + 35840);
  float* scr = (float*)(smem + 52224);
  const int t = threadIdx.x;
  const int m0 = blockIdx.x * 128;
  const int b = m0 >> 12;
  const int w = t >> 6, lane = t & 63;
  const int wm = (w >> 2) * 64, wn = (w & 3) * 64;
  const int lr = lane & 15, lk = lane >> 4;
  f32x4 acc[4][4] = {};
  float ksv[4];
#pragma unroll
  for (int fn = 0; fn < 4; ++fn) ksv[fn] = KSb[b * 256 + wn + fn * 16 + lr];
  // ---- phase 1: Q-proj GEMM (K=256) ----
  for (int kt = 0; kt < 4; ++kt) {
    __syncthreads();
#pragma unroll
    for (int i = 0; i < 2; ++i) {
      int id = t + i * 512, row = id >> 3, ch = (id & 7) << 3;
      GLDS16(cat + (size_t)(m0 + row) * 512 + kt * 64 + ch, sA + id * 8);
    }
#pragma unroll
    for (int i = 0; i < 4; ++i) {
      int id = t + i * 512, row = id >> 3, ch = (id & 7) << 3;
      GLDS16(WqT + (size_t)row * 256 + kt * 64 + ch, sB + id * 8);
    }
    __syncthreads();
    bf16x8 af[4][2], bfr[4][2];
#pragma unroll
    for (int f = 0; f < 4; ++f)
#pragma unroll
      for (int ks = 0; ks < 2; ++ks) {
        af[f][ks] = *(const bf16x8*)&sA[(wm + f * 16 + lr) * 64 + ks * 32 + lk * 8];
        bfr[f][ks] = *(const bf16x8*)&sB[(wn + f * 16 + lr) * 64 + ks * 32 + lk * 8];
      }
#pragma unroll
    for (int ks = 0; ks < 2; ++ks)
#pragma unroll
      for (int fm = 0; fm < 4; ++fm)
#pragma unroll
        for (int fn = 0; fn < 4; ++fn)
          acc[fm][fn] = __builtin_amdgcn_mfma_f32_16x16x32_bf16(
              af[fm][ks], bfr[fn][ks], acc[fm][fn], 0, 0, 0);
  }
  // ---- elu+1 and per-head z-scale (heads 32-col aligned within wave) ----
#pragma unroll
  for (int fm = 0; fm < 4; ++fm)
#pragma unroll
    for (int r = 0; r < 4; ++r) {
      float q[4];
#pragma unroll
      for (int fn = 0; fn < 4; ++fn) {
        float v = acc[fm][fn][r];
        q[fn] = v > 0.f ? v + 1.f : __expf(v);
      }
      float zd0 = q[0] * ksv[0] + q[1] * ksv[1];
      float zd1 = q[2] * ksv[2] + q[3] * ksv[3];
#pragma unroll
      for (int off = 1; off < 16; off <<= 1) {
        zd0 += __shfl_xor(zd0, off);
        zd1 += __shfl_xor(zd1, off);
      }
      float z0 = 4096.f / (zd0 + 1e-6f);
      float z1 = 4096.f / (zd1 + 1e-6f);
      acc[fm][0][r] = q[0] * z0; acc[fm][1][r] = q[1] * z0;
      acc[fm][2][r] = q[2] * z1; acc[fm][3][r] = q[3] * z1;
    }
  // ---- phase 2: msg = Qs @ Wcomb, two 128-col K-halves through Qlds --------
  f32x4 acc2[4][4] = {};
  const u16* Bw = wc + (size_t)b * 65536;
  for (int hh = 0; hh < 2; ++hh) {
    __syncthreads();                 // prior Qlds/sA/sB reads complete
    if ((wn >> 7) == hh) {           // this wave's cols are in [hh*128, hh*128+128)
#pragma unroll
      for (int fm = 0; fm < 4; ++fm)
#pragma unroll
        for (int fn = 0; fn < 4; ++fn)
#pragma unroll
          for (int r = 0; r < 4; ++r)
            Qlds[(wm + fm * 16 + lk * 4 + r) * 136 + (wn & 64) + fn * 16 + lr] =
                f2bf(acc[fm][fn][r]);
    }
    __syncthreads();                 // Qlds visible
    for (int kc2 = 0; kc2 < 4; ++kc2) {
#pragma unroll
      for (int i = 0; i < 2; ++i) {
        int id = t + i * 512, row = id >> 2, ch = (id & 3) << 3;
        GLDS16(Bw + (size_t)row * 256 + hh * 128 + kc2 * 32 +
                   (ch ^ ((row & 3) << 3)), sWc + id * 8);
      }
      __syncthreads();               // sWc staged
      bf16x8 a2[4], b2f[4];
#pragma unroll
      for (int f = 0; f < 4; ++f)
        a2[f] = *(const bf16x8*)&Qlds[(wm + f * 16 + lr) * 136 + kc2 * 32 + lk * 8];
#pragma unroll
      for (int fn = 0; fn < 4; ++fn) {
        int br = wn + fn * 16 + lr;
        b2f[fn] = *(const bf16x8*)&sWc[br * 32 + ((lk * 8) ^ ((br & 3) << 3))];
      }
#pragma unroll
      for (int fm = 0; fm < 4; ++fm)
#pragma unroll
        for (int fn = 0; fn < 4; ++fn)
          acc2[fm][fn] = __builtin_amdgcn_mfma_f32_16x16x32_bf16(
              a2[fm], b2f[fn], acc2[fm][fn], 0, 0, 0);
      __syncthreads();               // frag reads done before sWc/Qlds overwrite
    }
  }
  // ---- LN1 cross-wave ----
#pragma unroll
  for (int fm = 0; fm < 4; ++fm)
#pragma unroll
    for (int r = 0; r < 4; ++r) {
      float s = 0.f, sq = 0.f;
#pragma unroll
      for (int fn = 0; fn < 4; ++fn) {
        float a = acc2[fm][fn][r];
        s += a; sq += a * a;
      }
#pragma unroll
      for (int off = 1; off < 16; off <<= 1) {
        s += __shfl_xor(s, off);
        sq += __shfl_xor(sq, off);
      }
      if (lr == 0) {
        int row = wm + fm * 16 + lk * 4 + r;
        scr[row * 8 + (w & 3) * 2] = s;
        scr[row * 8 + (w & 3) * 2 + 1] = sq;
      }
    }
  __syncthreads();
  float gvs[4], bvs[4];
#pragma unroll
  for (int fn = 0; fn < 4; ++fn) {
    gvs[fn] = g1[wn + fn * 16 + lr];
    bvs[fn] = b1[wn + fn * 16 + lr];
  }
#pragma unroll
  for (int fm = 0; fm < 4; ++fm)
#pragma unroll
    for (int r = 0; r < 4; ++r) {
      int row = wm + fm * 16 + lk * 4 + r;
      float s = 0.f, sq = 0.f;
#pragma unroll
      for (int j = 0; j < 4; ++j) {
        s += scr[row * 8 + j * 2];
        sq += scr[row * 8 + j * 2 + 1];
      }
      float mu = s * (1.f / 256.f);
      float var = sq * (1.f / 256.f) - mu * mu;
      float rstd = rsqrtf(var + 1e-5f);
#pragma unroll
      for (int fn = 0; fn < 4; ++fn) {
        float y = (acc2[fm][fn][r] - mu) * rstd * gvs[fn] + bvs[fn];
        catout[(size_t)(m0 + row) * 512 + 256 + wn + fn * 16 + lr] = f2bf(y);
      }
    }
}

// ---- FUSED: MLP2 + LN2 + bf16-residual + transpose -> out -------------------
__global__ __launch_bounds__(512) void mlp2_tail_kernel(
    const u16* __restrict__ hidden, const u16* __restrict__ W2T,
    const float* __restrict__ g2, const float* __restrict__ b2,
    const u16* __restrict__ catp, float* __restrict__ out) {
  __shared__ alignas(16) char smem[16384 + 32768 + 4096 + 2048];
  u16* sA = (u16*)smem;                   // [128][64]
  u16* sB = (u16*)(smem + 16384);         // [256][64]
  float* scr = (float*)(smem + 49152);    // [128][8]
  float* sG = (float*)(smem + 53248);     // g2|b2
  float* T = (float*)smem;                // [64][129] overlay, post-GEMM
  const int t = threadIdx.x;
  const int m0 = blockIdx.x * 128;
  const int b = m0 >> 12, l0 = m0 & 4095;
  if (t < 256) { sG[t] = g2[t]; sG[256 + t] = b2[t]; }
  const int w = t >> 6, lane = t & 63;
  const int wm = (w >> 2) * 64, wn = (w & 3) * 64;
  const int lr = lane & 15, lk = lane >> 4;
  f32x4 acc[4][4] = {};
  for (int kt = 0; kt < 8; ++kt) {
    __syncthreads();
#pragma unroll
    for (int i = 0; i < 2; ++i) {
      int id = t + i * 512, row = id >> 3, chn = (id & 7) << 3;
      GLDS16(hidden + (size_t)(m0 + row) * 512 + kt * 64 + chn, sA + id * 8);
    }
#pragma unroll
    for (int i = 0; i < 4; ++i) {
      int id = t + i * 512, row = id >> 3, chn = (id & 7) << 3;
      GLDS16(W2T + (size_t)row * 512 + kt * 64 + chn, sB + id * 8);
    }
    __syncthreads();
    bf16x8 af[4][2], bfr[4][2];
#pragma unroll
    for (int f = 0; f < 4; ++f) {
#pragma unroll
      for (int ks = 0; ks < 2; ++ks) {
        af[f][ks] = *reinterpret_cast<const bf16x8*>(
            &sA[(wm + f * 16 + lr) * 64 + ks * 32 + lk * 8]);
        bfr[f][ks] = *reinterpret_cast<const bf16x8*>(
            &sB[(wn + f * 16 + lr) * 64 + ks * 32 + lk * 8]);
      }
    }
#pragma unroll
    for (int ks = 0; ks < 2; ++ks)
#pragma unroll
      for (int fm = 0; fm < 4; ++fm)
#pragma unroll
        for (int fn = 0; fn < 4; ++fn)
          acc[fm][fn] = __builtin_amdgcn_mfma_f32_16x16x32_bf16(
              af[fm][ks], bfr[fn][ks], acc[fm][fn], 0, 0, 0);
  }
  // ---- LN2 cross-wave ----
#pragma unroll
  for (int fm = 0; fm < 4; ++fm)
#pragma unroll
    for (int r = 0; r < 4; ++r) {
      float s = 0.f, sq = 0.f;
#pragma unroll
      for (int fn = 0; fn < 4; ++fn) {
        float a = acc[fm][fn][r];
        s += a; sq += a * a;
      }
#pragma unroll
      for (int off = 1; off < 16; off <<= 1) {
        s += __shfl_xor(s, off);
        sq += __shfl_xor(sq, off);
      }
      if (lr == 0) {
        int row = wm + fm * 16 + lk * 4 + r;
        scr[row * 8 + (w & 3) * 2] = s;
        scr[row * 8 + (w & 3) * 2 + 1] = sq;
      }
    }
  __syncthreads();
  float gvs[4], bvs[4];
#pragma unroll
  for (int fn = 0; fn < 4; ++fn) {
    gvs[fn] = sG[wn + fn * 16 + lr];
    bvs[fn] = sG[256 + wn + fn * 16 + lr];
  }
#pragma unroll
  for (int fm = 0; fm < 4; ++fm)
#pragma unroll
    for (int r = 0; r < 4; ++r) {
      int row = wm + fm * 16 + lk * 4 + r;
      float s = 0.f, sq = 0.f;
#pragma unroll
      for (int j = 0; j < 4; ++j) {
        s += scr[row * 8 + j * 2];
        sq += scr[row * 8 + j * 2 + 1];
      }
      float mu = s * (1.f / 256.f);
      float var = sq * (1.f / 256.f) - mu * mu;
      float rstd = rsqrtf(var + 1e-5f);
#pragma unroll
      for (int fn = 0; fn < 4; ++fn) {
        float xs = bf2f(catp[(size_t)(m0 + row) * 512 + wn + fn * 16 + lr]);
        acc[fm][fn][r] = (acc[fm][fn][r] - mu) * rstd * gvs[fn] + bvs[fn] + xs;
      }
    }
  __syncthreads();
  // ---- transpose chunks of 64 cols, coalesced f32 write ----
  for (int cc = 0; cc < 4; ++cc) {
    if ((w & 3) == cc) {
#pragma unroll
      for (int fm = 0; fm < 4; ++fm)
#pragma unroll
        for (int fn = 0; fn < 4; ++fn)
#pragma unroll
          for (int r = 0; r < 4; ++r)
            T[(fn * 16 + lr) * 129 + wm + fm * 16 + lk * 4 + r] = acc[fm][fn][r];
    }
    __syncthreads();
#pragma unroll
    for (int i = 0; i < 4; ++i) {
      int idx = t + i * 512;
      int cT = idx >> 5, lq = (idx & 31) * 4;
      int cg = cc * 64 + cT;
      size_t o = ((size_t)b * 256 + cg) * 4096 + l0 + lq;
      float4 ov;
      ov.x = T[cT * 129 + lq];
      ov.y = T[cT * 129 + lq + 1];
      ov.z = T[cT * 129 + lq + 2];
      ov.w = T[cT * 129 + lq + 3];
      *reinterpret_cast<float4*>(out + o) = ov;
    }
    __syncthreads();
  }
}

extern "C" void kernel_launch(void* const* d_in, const int* in_sizes, int n_in,
                              void* d_out, int out_size, void* d_ws, size_t ws_size,
                              hipStream_t stream) {
  (void)in_sizes; (void)n_in; (void)out_size; (void)ws_size;
  const float* x = (const float*)d_in[0];
  const float* srcp = (const float*)d_in[1];
  const float* Wq = (const float*)d_in[2];
  const float* Wk = (const float*)d_in[3];
  const float* Wv = (const float*)d_in[4];
  const float* Wm = (const float*)d_in[5];
  const float* W1 = (const float*)d_in[6];
  const float* W2 = (const float*)d_in[7];
  const float* g1 = (const float*)d_in[8];
  const float* b1 = (const float*)d_in[9];
  const float* g2 = (const float*)d_in[10];
  const float* b2 = (const float*)d_in[11];
  float* out = (float*)d_out;
  char* ws = (char*)d_ws;

  u16* wqt = (u16*)(ws + OFF_WQ);
  u16* wkvt = (u16*)(ws + OFF_WK);
  u16* wkt = (u16*)(ws + OFF_WK);
  u16* wvt = (u16*)(ws + OFF_WV);
  u16* wmt = (u16*)(ws + OFF_WM);
  u16* w1t = (u16*)(ws + OFF_W1);
  u16* w2t = (u16*)(ws + OFF_W2);
  u16* cat = (u16*)(ws + OFF_CAT);
  u16* ssb = (u16*)(ws + OFF_SSB);
  u16* kvproj = (u16*)(ws + OFF_KVPROJ);
  float* KSb = (float*)(ws + OFF_KS);
  float* KVp = (float*)(ws + OFF_KVP);
  float* KSp = (float*)(ws + OFF_KSP);
  u16* wcombT = (u16*)(ws + OFF_WC);
  u16* hidden = kvproj;                // reuse after kv_partial consumed kvproj

  dim3 blk(256);
  wprep_all_kernel<<<dim3(640), blk, 0, stream>>>(Wq, Wk, Wv, Wm, W1, W2,
                                                  wqt, wkt, wvt, wmt, w1t, w2t);
  transpose_in_kernel<<<dim3(64, 4, 16), blk, 0, stream>>>(x, srcp, cat, ssb);
  gemm256_kernel<4><<<dim3(512), dim3(512), 0, stream>>>(ssb, 256, wkvt, 256, kvproj, 512);
  kv_partial_kernel<<<dim3(64, 8), blk, 0, stream>>>(kvproj, KVp, KSp);
  kvred_wcomb_kernel<<<dim3(64), blk, 0, stream>>>(KVp, KSp, wmt, wcombT, KSb);
  qmsg_kernel<<<dim3(256), dim3(512), 0, stream>>>(cat, wqt, KSb, wcombT, g1, b1, cat);
  gemm256_kernel<3><<<dim3(512), dim3(512), 0, stream>>>(cat, 512, w1t, 512, hidden, 512);
  mlp2_tail_kernel<<<dim3(256), dim3(512), 0, stream>>>(hidden, w2t, g2, b2, cat, out);
}